// Round 1
// baseline (357.132 us; speedup 1.0000x reference)
//
#include <hip/hip_runtime.h>
#include <stdint.h>

#define BSZ 2
#define TT 2048
#define DD 1024
#define HH 16
#define HD 64

typedef __bf16 bf16x8 __attribute__((ext_vector_type(8)));
typedef float f32x4 __attribute__((ext_vector_type(4)));

__device__ __forceinline__ unsigned short f2bf(float f) {
    union { float f; unsigned u; } c; c.f = f;
    unsigned u = c.u;
    unsigned r = u + 0x7fffu + ((u >> 16) & 1u);
    return (unsigned short)(r >> 16);
}

union U4BF { uint4 u; bf16x8 b; };
__device__ __forceinline__ bf16x8 as_bf8(uint4 v) { U4BF c; c.u = v; return c.b; }

// ---------------- fp32 -> bf16 convert ----------------
__global__ void cvt_bf16(const float* __restrict__ in, ushort* __restrict__ out, int n4) {
    int i = blockIdx.x * blockDim.x + threadIdx.x;
    if (i < n4) {
        float4 v = ((const float4*)in)[i];
        ushort4 o;
        o.x = f2bf(v.x); o.y = f2bf(v.y); o.z = f2bf(v.z); o.w = f2bf(v.w);
        ((ushort4*)out)[i] = o;
    }
}

// ---------------- W transpose + convert: Wt[n][k] = bf16(W[k][n]) ----------------
__global__ void wtrans(const float* __restrict__ W0, const float* __restrict__ W1,
                       const float* __restrict__ W2, const float* __restrict__ W3,
                       ushort* __restrict__ T0, ushort* __restrict__ T1,
                       ushort* __restrict__ T2, ushort* __restrict__ T3) {
    __shared__ float sh[32][33];
    const float* src; ushort* dst;
    switch (blockIdx.z) {
        case 0:  src = W0; dst = T0; break;
        case 1:  src = W1; dst = T1; break;
        case 2:  src = W2; dst = T2; break;
        default: src = W3; dst = T3; break;
    }
    int k0 = blockIdx.y * 32, n0 = blockIdx.x * 32;
    int tx = threadIdx.x, ty = threadIdx.y;
    sh[ty][tx] = src[(size_t)(k0 + ty) * DD + n0 + tx];
    __syncthreads();
    dst[(size_t)(n0 + ty) * DD + k0 + tx] = f2bf(sh[tx][ty]);
}

// ---------------- 128x128 bf16 MFMA GEMM: C = A @ Bt^T + bias ----------------
// A: [4096][1024] bf16 row-major. Bt: [1024 n][1024 k] bf16 (W transposed).
// OUT_MODE 0: bf16 out to [B][H][T][hd]. OUT_MODE 1: fp32 out row-major [4096][1024].
template<int OUT_MODE>
__global__ __launch_bounds__(256)
void gemm128(const ushort* __restrict__ A, const ushort* __restrict__ Bt,
             const float* __restrict__ bias, void* __restrict__ outp) {
    __shared__ __attribute__((aligned(16))) ushort As[128][40];
    __shared__ __attribute__((aligned(16))) ushort Bs[128][40];
    const int tid  = threadIdx.x;
    const int lane = tid & 63, w = tid >> 6;
    const int wr = w >> 1, wc = w & 1;
    const int ln = lane & 15, quad = lane >> 4;
    const int m0 = blockIdx.y * 128, n0 = blockIdx.x * 128;

    const f32x4 zero = {0.f, 0.f, 0.f, 0.f};
    f32x4 acc[4][4];
    #pragma unroll
    for (int i = 0; i < 4; ++i)
        #pragma unroll
        for (int j = 0; j < 4; ++j) acc[i][j] = zero;

    const int sr  = tid >> 2;       // 0..63
    const int sc8 = (tid & 3) * 8;  // 0,8,16,24

    for (int kb = 0; kb < 1024; kb += 32) {
        #pragma unroll
        for (int it = 0; it < 2; ++it) {
            int r = sr + it * 64;
            uint4 va = *(const uint4*)(A  + (size_t)(m0 + r) * 1024 + kb + sc8);
            *(uint4*)&As[r][sc8] = va;
            uint4 vb = *(const uint4*)(Bt + (size_t)(n0 + r) * 1024 + kb + sc8);
            *(uint4*)&Bs[r][sc8] = vb;
        }
        __syncthreads();
        bf16x8 af[4], bfr[4];
        #pragma unroll
        for (int i = 0; i < 4; ++i)
            af[i] = as_bf8(*(const uint4*)&As[wr * 64 + i * 16 + ln][quad * 8]);
        #pragma unroll
        for (int j = 0; j < 4; ++j)
            bfr[j] = as_bf8(*(const uint4*)&Bs[wc * 64 + j * 16 + ln][quad * 8]);
        #pragma unroll
        for (int i = 0; i < 4; ++i)
            #pragma unroll
            for (int j = 0; j < 4; ++j)
                acc[i][j] = __builtin_amdgcn_mfma_f32_16x16x32_bf16(af[i], bfr[j], acc[i][j], 0, 0, 0);
        __syncthreads();
    }

    #pragma unroll
    for (int j = 0; j < 4; ++j) {
        int n = n0 + wc * 64 + j * 16 + ln;
        float bv = bias[n];
        #pragma unroll
        for (int i = 0; i < 4; ++i) {
            #pragma unroll
            for (int r = 0; r < 4; ++r) {
                int m = m0 + wr * 64 + i * 16 + quad * 4 + r;
                float v = acc[i][j][r] + bv;
                if (OUT_MODE == 0) {
                    int b = m >> 11, t = m & 2047, h = n >> 6, d = n & 63;
                    ((ushort*)outp)[(((size_t)(b * HH + h)) * TT + t) * HD + d] = f2bf(v);
                } else {
                    ((float*)outp)[(size_t)m * 1024 + n] = v;
                }
            }
        }
    }
}

// ---------------- flash attention with ALiBi ----------------
__global__ __launch_bounds__(256)
void attn_kernel(const ushort* __restrict__ Qh, const ushort* __restrict__ Kh,
                 const ushort* __restrict__ Vh, ushort* __restrict__ outp) {
    __shared__ __attribute__((aligned(16))) ushort Ks[64][72];
    __shared__ __attribute__((aligned(16))) ushort Vt[64][72];  // Vt[d][kpos]
    __shared__ __attribute__((aligned(16))) ushort Ps[4][16][72];
    const int tid  = threadIdx.x;
    const int lane = tid & 63, w = tid >> 6;
    const int ln = lane & 15, quad = lane >> 4;
    const int bh = blockIdx.y;           // b*16 + h
    const int h = bh & 15;
    const int qbase = blockIdx.x * 64;
    const float slope = exp2f(-0.5f * (float)(h + 1));
    const float scale = 0.125f;
    const size_t base = (size_t)bh * TT * HD;

    // Q fragments in registers (A-layout: m=lane&15, k=quad*8+j)
    const int qrow = qbase + w * 16 + ln;
    bf16x8 qa0, qa1;
    {
        const uint4* qp = (const uint4*)(Qh + base + (size_t)qrow * HD);
        qa0 = as_bf8(qp[quad]);
        qa1 = as_bf8(qp[4 + quad]);
    }
    const f32x4 zero = {0.f, 0.f, 0.f, 0.f};
    f32x4 o[4];
    float mrow[4], lrow[4];
    #pragma unroll
    for (int r = 0; r < 4; ++r) { o[r] = zero; mrow[r] = -1e30f; lrow[r] = 0.f; }
    const int qg = qbase + w * 16 + quad * 4;  // + r

    for (int kt = 0; kt < TT / 64; ++kt) {
        __syncthreads();  // prior iteration's LDS reads done
        // stage K tile [kpos][d]
        {
            int r0 = tid >> 3;
            int c8 = (tid & 7) * 8;
            #pragma unroll
            for (int it = 0; it < 2; ++it) {
                int kp = r0 + it * 32;
                *(uint4*)&Ks[kp][c8] =
                    *(const uint4*)(Kh + base + (size_t)(kt * 64 + kp) * HD + c8);
            }
            // stage V transposed: Vt[d][kpos]
            int d = tid & 63;
            int kp0 = (tid >> 6) * 8;
            #pragma unroll
            for (int it = 0; it < 2; ++it) {
                int kp = kp0 + it * 32;
                alignas(16) ushort tmp[8];
                #pragma unroll
                for (int p = 0; p < 8; ++p)
                    tmp[p] = Vh[base + (size_t)(kt * 64 + kp + p) * HD + d];
                *(uint4*)&Vt[d][kp] = *(const uint4*)tmp;
            }
        }
        __syncthreads();

        // S = Q K^T  (rows=q, cols=kpos)
        f32x4 s[4];
        #pragma unroll
        for (int n = 0; n < 4; ++n) {
            bf16x8 b0 = as_bf8(*(const uint4*)&Ks[n * 16 + ln][quad * 8]);
            bf16x8 b1 = as_bf8(*(const uint4*)&Ks[n * 16 + ln][32 + quad * 8]);
            f32x4 z = zero;
            z    = __builtin_amdgcn_mfma_f32_16x16x32_bf16(qa0, b0, z, 0, 0, 0);
            s[n] = __builtin_amdgcn_mfma_f32_16x16x32_bf16(qa1, b1, z, 0, 0, 0);
        }

        // scale + ALiBi bias, online softmax
        float rmax[4] = {-1e30f, -1e30f, -1e30f, -1e30f};
        #pragma unroll
        for (int n = 0; n < 4; ++n) {
            int kg = kt * 64 + n * 16 + ln;
            #pragma unroll
            for (int r = 0; r < 4; ++r) {
                int di = qg + r - kg;
                float v = s[n][r] * scale - slope * fabsf((float)di);
                s[n][r] = v;
                rmax[r] = fmaxf(rmax[r], v);
            }
        }
        #pragma unroll
        for (int r = 0; r < 4; ++r) {
            #pragma unroll
            for (int msk = 1; msk <= 8; msk <<= 1)
                rmax[r] = fmaxf(rmax[r], __shfl_xor(rmax[r], msk, 64));
        }
        float alpha[4], rsum[4];
        #pragma unroll
        for (int r = 0; r < 4; ++r) {
            float mn = fmaxf(mrow[r], rmax[r]);
            alpha[r] = __expf(mrow[r] - mn);
            mrow[r] = mn;
            rsum[r] = 0.f;
        }
        #pragma unroll
        for (int n = 0; n < 4; ++n)
            #pragma unroll
            for (int r = 0; r < 4; ++r) {
                float p = __expf(s[n][r] - mrow[r]);
                s[n][r] = p;
                rsum[r] += p;
            }
        #pragma unroll
        for (int r = 0; r < 4; ++r) {
            #pragma unroll
            for (int msk = 1; msk <= 8; msk <<= 1)
                rsum[r] += __shfl_xor(rsum[r], msk, 64);
            lrow[r] = lrow[r] * alpha[r] + rsum[r];
        }
        #pragma unroll
        for (int dn = 0; dn < 4; ++dn)
            #pragma unroll
            for (int r = 0; r < 4; ++r)
                o[dn][r] *= alpha[r];

        // P: C-layout -> LDS -> A-layout
        #pragma unroll
        for (int n = 0; n < 4; ++n)
            #pragma unroll
            for (int r = 0; r < 4; ++r)
                Ps[w][quad * 4 + r][n * 16 + ln] = f2bf(s[n][r]);
        __syncthreads();

        // O += P V
        #pragma unroll
        for (int half = 0; half < 2; ++half) {
            bf16x8 ap = as_bf8(*(const uint4*)&Ps[w][ln][half * 32 + quad * 8]);
            #pragma unroll
            for (int dn = 0; dn < 4; ++dn) {
                bf16x8 bv = as_bf8(*(const uint4*)&Vt[dn * 16 + ln][half * 32 + quad * 8]);
                o[dn] = __builtin_amdgcn_mfma_f32_16x16x32_bf16(ap, bv, o[dn], 0, 0, 0);
            }
        }
    }

    // epilogue: normalize and write [B][T][D] bf16
    const int b = bh >> 4;
    #pragma unroll
    for (int r = 0; r < 4; ++r) {
        float inv = 1.0f / lrow[r];
        int q = qg + r;
        size_t ob = ((size_t)(b * TT + q)) * DD + h * HD;
        #pragma unroll
        for (int dn = 0; dn < 4; ++dn)
            outp[ob + dn * 16 + ln] = f2bf(o[dn][r] * inv);
    }
}

extern "C" void kernel_launch(void* const* d_in, const int* in_sizes, int n_in,
                              void* d_out, int out_size, void* d_ws, size_t ws_size,
                              hipStream_t stream) {
    const float* query = (const float*)d_in[0];
    const float* key   = (const float*)d_in[1];
    const float* value = (const float*)d_in[2];
    const float* Wq = (const float*)d_in[3];
    const float* bq = (const float*)d_in[4];
    const float* Wk = (const float*)d_in[5];
    const float* bk = (const float*)d_in[6];
    const float* Wv = (const float*)d_in[7];
    const float* bv = (const float*)d_in[8];
    const float* Wo = (const float*)d_in[9];
    const float* bo = (const float*)d_in[10];
    float* out = (float*)d_out;

    char* ws = (char*)d_ws;
    const size_t MB = 1024 * 1024;
    ushort* Xq  = (ushort*)(ws + 0);
    ushort* Xk  = (ushort*)(ws + 8 * MB);
    ushort* Xv  = (ushort*)(ws + 16 * MB);
    ushort* Wtq = (ushort*)(ws + 24 * MB);
    ushort* Wtk = (ushort*)(ws + 26 * MB);
    ushort* Wtv = (ushort*)(ws + 28 * MB);
    ushort* Wto = (ushort*)(ws + 30 * MB);
    ushort* Qh  = (ushort*)(ws + 32 * MB);
    ushort* Kh  = (ushort*)(ws + 40 * MB);
    ushort* Vh  = (ushort*)(ws + 48 * MB);
    ushort* attn = (ushort*)(ws + 0);  // reuse Xq region (free after Q projection)

    const int n4 = (BSZ * TT * DD) / 4;  // 1048576
    cvt_bf16<<<dim3(n4 / 256), 256, 0, stream>>>(query, Xq, n4);
    cvt_bf16<<<dim3(n4 / 256), 256, 0, stream>>>(key,   Xk, n4);
    cvt_bf16<<<dim3(n4 / 256), 256, 0, stream>>>(value, Xv, n4);
    wtrans<<<dim3(32, 32, 4), dim3(32, 32), 0, stream>>>(Wq, Wk, Wv, Wo, Wtq, Wtk, Wtv, Wto);

    gemm128<0><<<dim3(8, 32), 256, 0, stream>>>(Xq, Wtq, bq, Qh);
    gemm128<0><<<dim3(8, 32), 256, 0, stream>>>(Xk, Wtk, bk, Kh);
    gemm128<0><<<dim3(8, 32), 256, 0, stream>>>(Xv, Wtv, bv, Vh);

    attn_kernel<<<dim3(TT / 64, BSZ * HH), 256, 0, stream>>>(Qh, Kh, Vh, attn);

    gemm128<1><<<dim3(8, 32), 256, 0, stream>>>(attn, Wto, bo, out);
}

// Round 2
// 352.105 us; speedup vs baseline: 1.0143x; 1.0143x over previous
//
#include <hip/hip_runtime.h>
#include <stdint.h>

#define BSZ 2
#define TT 2048
#define DD 1024
#define HH 16
#define HD 64

typedef __bf16 bf16x8 __attribute__((ext_vector_type(8)));
typedef float f32x4 __attribute__((ext_vector_type(4)));

#if __has_builtin(__builtin_amdgcn_exp2f)
#define EXP2(x) __builtin_amdgcn_exp2f(x)
#else
#define EXP2(x) exp2f(x)
#endif

__device__ __forceinline__ unsigned short f2bf(float f) {
    union { float f; unsigned u; } c; c.f = f;
    unsigned u = c.u;
    unsigned r = u + 0x7fffu + ((u >> 16) & 1u);
    return (unsigned short)(r >> 16);
}
__device__ __forceinline__ unsigned fasu(float f) {
    union { float f; unsigned u; } c; c.f = f; return c.u;
}

union U4BF { uint4 u; bf16x8 b; };
__device__ __forceinline__ bf16x8 as_bf8(uint4 v) { U4BF c; c.u = v; return c.b; }

// ---------------- fp32 -> bf16 convert ----------------
__global__ void cvt_bf16(const float* __restrict__ in, ushort* __restrict__ out, int n4) {
    int i = blockIdx.x * blockDim.x + threadIdx.x;
    if (i < n4) {
        float4 v = ((const float4*)in)[i];
        ushort4 o;
        o.x = f2bf(v.x); o.y = f2bf(v.y); o.z = f2bf(v.z); o.w = f2bf(v.w);
        ((ushort4*)out)[i] = o;
    }
}

// ---------------- W transpose + convert: Wt[n][k] = bf16(W[k][n]) ----------------
__global__ void wtrans(const float* __restrict__ W0, const float* __restrict__ W1,
                       const float* __restrict__ W2, const float* __restrict__ W3,
                       ushort* __restrict__ T0, ushort* __restrict__ T1,
                       ushort* __restrict__ T2, ushort* __restrict__ T3) {
    __shared__ float sh[32][33];
    const float* src; ushort* dst;
    switch (blockIdx.z) {
        case 0:  src = W0; dst = T0; break;
        case 1:  src = W1; dst = T1; break;
        case 2:  src = W2; dst = T2; break;
        default: src = W3; dst = T3; break;
    }
    int k0 = blockIdx.y * 32, n0 = blockIdx.x * 32;
    int tx = threadIdx.x, ty = threadIdx.y;
    sh[ty][tx] = src[(size_t)(k0 + ty) * DD + n0 + tx];
    __syncthreads();
    dst[(size_t)(n0 + ty) * DD + k0 + tx] = f2bf(sh[tx][ty]);
}

// ---------------- V transpose: Vt[bh][d][t] = Vh[bh][t][d] ----------------
__global__ __launch_bounds__(256)
void vtrans(const ushort* __restrict__ Vh, ushort* __restrict__ Vt) {
    __shared__ ushort sh[64][72];
    const int tid = threadIdx.x;
    const int bh = blockIdx.y;
    const int t0 = blockIdx.x * 64;
    const size_t base = (size_t)bh * (TT * HD);
    #pragma unroll
    for (int it = 0; it < 2; ++it) {
        int u = tid + it * 256;
        int r = u >> 3, c8 = (u & 7) * 8;
        *(uint4*)&sh[r][c8] = *(const uint4*)(Vh + base + (size_t)(t0 + r) * HD + c8);
    }
    __syncthreads();
    #pragma unroll
    for (int it = 0; it < 2; ++it) {
        int u = tid + it * 256;
        int d = u >> 3, c8 = (u & 7) * 8;  // c8 = t offset
        alignas(16) ushort tmp[8];
        #pragma unroll
        for (int p = 0; p < 8; ++p) tmp[p] = sh[c8 + p][d];
        *(uint4*)(Vt + base + (size_t)d * TT + t0 + c8) = *(const uint4*)tmp;
    }
}

// ---------------- 128x128 bf16 MFMA GEMM: C = A @ Bt^T + bias ----------------
template<int OUT_MODE>
__global__ __launch_bounds__(256)
void gemm128(const ushort* __restrict__ A, const ushort* __restrict__ Bt,
             const float* __restrict__ bias, void* __restrict__ outp) {
    __shared__ __attribute__((aligned(16))) ushort As[128][40];
    __shared__ __attribute__((aligned(16))) ushort Bs[128][40];
    const int tid  = threadIdx.x;
    const int lane = tid & 63, w = tid >> 6;
    const int wr = w >> 1, wc = w & 1;
    const int ln = lane & 15, quad = lane >> 4;
    const int m0 = blockIdx.y * 128, n0 = blockIdx.x * 128;

    const f32x4 zero = {0.f, 0.f, 0.f, 0.f};
    f32x4 acc[4][4];
    #pragma unroll
    for (int i = 0; i < 4; ++i)
        #pragma unroll
        for (int j = 0; j < 4; ++j) acc[i][j] = zero;

    const int sr  = tid >> 2;
    const int sc8 = (tid & 3) * 8;

    for (int kb = 0; kb < 1024; kb += 32) {
        #pragma unroll
        for (int it = 0; it < 2; ++it) {
            int r = sr + it * 64;
            uint4 va = *(const uint4*)(A  + (size_t)(m0 + r) * 1024 + kb + sc8);
            *(uint4*)&As[r][sc8] = va;
            uint4 vb = *(const uint4*)(Bt + (size_t)(n0 + r) * 1024 + kb + sc8);
            *(uint4*)&Bs[r][sc8] = vb;
        }
        __syncthreads();
        bf16x8 af[4], bfr[4];
        #pragma unroll
        for (int i = 0; i < 4; ++i)
            af[i] = as_bf8(*(const uint4*)&As[wr * 64 + i * 16 + ln][quad * 8]);
        #pragma unroll
        for (int j = 0; j < 4; ++j)
            bfr[j] = as_bf8(*(const uint4*)&Bs[wc * 64 + j * 16 + ln][quad * 8]);
        #pragma unroll
        for (int i = 0; i < 4; ++i)
            #pragma unroll
            for (int j = 0; j < 4; ++j)
                acc[i][j] = __builtin_amdgcn_mfma_f32_16x16x32_bf16(af[i], bfr[j], acc[i][j], 0, 0, 0);
        __syncthreads();
    }

    #pragma unroll
    for (int j = 0; j < 4; ++j) {
        int n = n0 + wc * 64 + j * 16 + ln;
        float bv = bias[n];
        #pragma unroll
        for (int i = 0; i < 4; ++i) {
            #pragma unroll
            for (int r = 0; r < 4; ++r) {
                int m = m0 + wr * 64 + i * 16 + quad * 4 + r;
                float v = acc[i][j][r] + bv;
                if (OUT_MODE == 0) {
                    int b = m >> 11, t = m & 2047, h = n >> 6, d = n & 63;
                    ((ushort*)outp)[(((size_t)(b * HH + h)) * TT + t) * HD + d] = f2bf(v);
                } else {
                    ((float*)outp)[(size_t)m * 1024 + n] = v;
                }
            }
        }
    }
}

// ---------------- flash attention, no-max softmax + ALiBi ----------------
// Qh,Kh: [bh][t][d]   Vtg: [bh][d][t]   out: [B][T][D] bf16
__global__ __launch_bounds__(256)
void attn_kernel(const ushort* __restrict__ Qh, const ushort* __restrict__ Kh,
                 const ushort* __restrict__ Vtg, ushort* __restrict__ outp) {
    __shared__ __attribute__((aligned(16))) ushort Ks[64][72];
    __shared__ __attribute__((aligned(16))) ushort Vs[64][72];   // [d][kpos]
    __shared__ __attribute__((aligned(16))) ushort Ps[4][32][72];
    const int tid  = threadIdx.x;
    const int lane = tid & 63, w = tid >> 6;
    const int ln = lane & 15, quad = lane >> 4;
    const int bh = blockIdx.y;
    const int h = bh & 15, b = bh >> 4;
    const int qbase = blockIdx.x * 128 + w * 32;
    const float slope2 = exp2f(-0.5f * (float)(h + 1)) * 1.44269504f;  // slope*log2e
    const float c1 = 0.125f * 1.44269504f;                             // scale*log2e
    const size_t base = (size_t)bh * (TT * HD);  // == bh*64*2048 for Vtg too

    // Q fragments (A-layout): qa[g][half]
    bf16x8 qa[2][2];
    #pragma unroll
    for (int g = 0; g < 2; ++g) {
        const uint4* qp = (const uint4*)(Qh + base + (size_t)(qbase + g * 16 + ln) * HD);
        qa[g][0] = as_bf8(qp[quad]);
        qa[g][1] = as_bf8(qp[4 + quad]);
    }
    const f32x4 zero = {0.f, 0.f, 0.f, 0.f};
    f32x4 o[2][4], lsum[2];
    #pragma unroll
    for (int g = 0; g < 2; ++g) {
        lsum[g] = zero;
        #pragma unroll
        for (int dn = 0; dn < 4; ++dn) o[g][dn] = zero;
    }
    bf16x8 ones;
    {
        union { ushort us[8]; bf16x8 v; } uu;
        #pragma unroll
        for (int p = 0; p < 8; ++p) uu.us[p] = 0x3F80;  // bf16 1.0
        ones = uu.v;
    }
    float qrf[2][4];
    #pragma unroll
    for (int g = 0; g < 2; ++g)
        #pragma unroll
        for (int r = 0; r < 4; ++r)
            qrf[g][r] = (float)(qbase + g * 16 + quad * 4 + r);

    // staging addresses: 512 uint4 per 64x64 tile, 2 per thread
    const int sr  = tid >> 3;        // 0..31 (+32 on it=1)
    const int sc8 = (tid & 7) * 8;   // 0..56

    uint4 pk[2], pv[2];
    {
        #pragma unroll
        for (int it = 0; it < 2; ++it) {
            int r = sr + it * 32;
            pk[it] = *(const uint4*)(Kh  + base + (size_t)r * HD + sc8);
            pv[it] = *(const uint4*)(Vtg + base + (size_t)r * TT + sc8);
        }
    }

    for (int kt = 0; kt < TT / 64; ++kt) {
        #pragma unroll
        for (int it = 0; it < 2; ++it) {
            int r = sr + it * 32;
            *(uint4*)&Ks[r][sc8] = pk[it];
            *(uint4*)&Vs[r][sc8] = pv[it];
        }
        __syncthreads();
        if (kt + 1 < TT / 64) {
            int k0 = (kt + 1) * 64;
            #pragma unroll
            for (int it = 0; it < 2; ++it) {
                int r = sr + it * 32;
                pk[it] = *(const uint4*)(Kh  + base + (size_t)(k0 + r) * HD + sc8);
                pv[it] = *(const uint4*)(Vtg + base + (size_t)r * TT + k0 + sc8);
            }
        }

        // S = Q K^T
        f32x4 s[2][4];
        #pragma unroll
        for (int n = 0; n < 4; ++n) {
            bf16x8 b0 = as_bf8(*(const uint4*)&Ks[n * 16 + ln][quad * 8]);
            bf16x8 b1 = as_bf8(*(const uint4*)&Ks[n * 16 + ln][32 + quad * 8]);
            #pragma unroll
            for (int g = 0; g < 2; ++g) {
                f32x4 z = zero;
                z = __builtin_amdgcn_mfma_f32_16x16x32_bf16(qa[g][0], b0, z, 0, 0, 0);
                s[g][n] = __builtin_amdgcn_mfma_f32_16x16x32_bf16(qa[g][1], b1, z, 0, 0, 0);
            }
        }

        // p = exp2(S*c1 - slope2*|q-k|), truncate to bf16, swizzled store
        #pragma unroll
        for (int n = 0; n < 4; ++n) {
            float kg = (float)(kt * 64 + n * 16 + ln);
            int bswz = ((2 * n + (ln >> 3)) ^ quad) * 8 + (ln & 7);
            #pragma unroll
            for (int g = 0; g < 2; ++g) {
                #pragma unroll
                for (int r = 0; r < 4; ++r) {
                    float d = qrf[g][r] - kg;
                    float arg = fmaf(s[g][n][r], c1, -slope2 * fabsf(d));
                    float p = EXP2(arg);
                    Ps[w][g * 16 + quad * 4 + r][bswz] = (ushort)(fasu(p) >> 16);
                }
            }
        }
        __syncthreads();

        // O += P V ; lsum += P * ones
        #pragma unroll
        for (int half = 0; half < 2; ++half) {
            bf16x8 ap0 = as_bf8(*(const uint4*)&Ps[w][ln]     [(((half * 4 + quad) ^ (ln >> 2))) * 8]);
            bf16x8 ap1 = as_bf8(*(const uint4*)&Ps[w][16 + ln][(((half * 4 + quad) ^ (ln >> 2))) * 8]);
            #pragma unroll
            for (int dn = 0; dn < 4; ++dn) {
                bf16x8 bv = as_bf8(*(const uint4*)&Vs[dn * 16 + ln][half * 32 + quad * 8]);
                o[0][dn] = __builtin_amdgcn_mfma_f32_16x16x32_bf16(ap0, bv, o[0][dn], 0, 0, 0);
                o[1][dn] = __builtin_amdgcn_mfma_f32_16x16x32_bf16(ap1, bv, o[1][dn], 0, 0, 0);
            }
            lsum[0] = __builtin_amdgcn_mfma_f32_16x16x32_bf16(ap0, ones, lsum[0], 0, 0, 0);
            lsum[1] = __builtin_amdgcn_mfma_f32_16x16x32_bf16(ap1, ones, lsum[1], 0, 0, 0);
        }
        __syncthreads();
    }

    // epilogue: normalize, write [B][T][D] bf16
    #pragma unroll
    for (int g = 0; g < 2; ++g) {
        #pragma unroll
        for (int r = 0; r < 4; ++r) {
            float inv = __builtin_amdgcn_rcpf(lsum[g][r]);
            int q = qbase + g * 16 + quad * 4 + r;
            size_t ob = ((size_t)(b * TT + q)) * DD + h * HD;
            #pragma unroll
            for (int dn = 0; dn < 4; ++dn)
                outp[ob + dn * 16 + ln] = f2bf(o[g][dn][r] * inv);
        }
    }
}

extern "C" void kernel_launch(void* const* d_in, const int* in_sizes, int n_in,
                              void* d_out, int out_size, void* d_ws, size_t ws_size,
                              hipStream_t stream) {
    const float* query = (const float*)d_in[0];
    const float* key   = (const float*)d_in[1];
    const float* value = (const float*)d_in[2];
    const float* Wq = (const float*)d_in[3];
    const float* bq = (const float*)d_in[4];
    const float* Wk = (const float*)d_in[5];
    const float* bk = (const float*)d_in[6];
    const float* Wv = (const float*)d_in[7];
    const float* bv = (const float*)d_in[8];
    const float* Wo = (const float*)d_in[9];
    const float* bo = (const float*)d_in[10];
    float* out = (float*)d_out;

    char* ws = (char*)d_ws;
    const size_t MB = 1024 * 1024;
    ushort* Xq  = (ushort*)(ws + 0);
    ushort* Xk  = (ushort*)(ws + 8 * MB);
    ushort* Xv  = (ushort*)(ws + 16 * MB);
    ushort* Wtq = (ushort*)(ws + 24 * MB);
    ushort* Wtk = (ushort*)(ws + 26 * MB);
    ushort* Wtv = (ushort*)(ws + 28 * MB);
    ushort* Wto = (ushort*)(ws + 30 * MB);
    ushort* Qh  = (ushort*)(ws + 32 * MB);
    ushort* Kh  = (ushort*)(ws + 40 * MB);
    ushort* Vh  = (ushort*)(ws + 48 * MB);
    ushort* Vt   = (ushort*)(ws + 8 * MB);  // reuse Xk (free after K projection)
    ushort* attn = (ushort*)(ws + 0);       // reuse Xq (free after Q projection)

    const int n4 = (BSZ * TT * DD) / 4;
    cvt_bf16<<<dim3(n4 / 256), 256, 0, stream>>>(query, Xq, n4);
    cvt_bf16<<<dim3(n4 / 256), 256, 0, stream>>>(key,   Xk, n4);
    cvt_bf16<<<dim3(n4 / 256), 256, 0, stream>>>(value, Xv, n4);
    wtrans<<<dim3(32, 32, 4), dim3(32, 32), 0, stream>>>(Wq, Wk, Wv, Wo, Wtq, Wtk, Wtv, Wto);

    gemm128<0><<<dim3(8, 32), 256, 0, stream>>>(Xq, Wtq, bq, Qh);
    gemm128<0><<<dim3(8, 32), 256, 0, stream>>>(Xk, Wtk, bk, Kh);
    gemm128<0><<<dim3(8, 32), 256, 0, stream>>>(Xv, Wtv, bv, Vh);

    vtrans<<<dim3(TT / 64, BSZ * HH), 256, 0, stream>>>(Vh, Vt);

    attn_kernel<<<dim3(TT / 128, BSZ * HH), 256, 0, stream>>>(Qh, Kh, Vt, attn);

    gemm128<1><<<dim3(8, 32), 256, 0, stream>>>(attn, Wto, bo, out);
}

// Round 3
// 304.731 us; speedup vs baseline: 1.1720x; 1.1555x over previous
//
#include <hip/hip_runtime.h>
#include <stdint.h>

#define BSZ 2
#define TT 2048
#define DD 1024
#define HH 16
#define HD 64

typedef __bf16 bf16x8 __attribute__((ext_vector_type(8)));
typedef float f32x4 __attribute__((ext_vector_type(4)));

#if __has_builtin(__builtin_amdgcn_exp2f)
#define EXP2(x) __builtin_amdgcn_exp2f(x)
#else
#define EXP2(x) exp2f(x)
#endif

__device__ __forceinline__ unsigned short f2bf(float f) {
    union { float f; unsigned u; } c; c.f = f;
    unsigned u = c.u;
    unsigned r = u + 0x7fffu + ((u >> 16) & 1u);
    return (unsigned short)(r >> 16);
}
__device__ __forceinline__ unsigned fasu(float f) {
    union { float f; unsigned u; } c; c.f = f; return c.u;
}

union U4BF { uint4 u; bf16x8 b; };
__device__ __forceinline__ bf16x8 as_bf8(uint4 v) { U4BF c; c.u = v; return c.b; }

// ---------------- fp32 -> bf16 convert, 3 tensors in one launch ----------------
__global__ void cvt3(const float* __restrict__ q, const float* __restrict__ k,
                     const float* __restrict__ v, ushort* __restrict__ xq,
                     ushort* __restrict__ xk, ushort* __restrict__ xv, int n4) {
    int z = blockIdx.y;
    const float* in = (z == 0) ? q : (z == 1) ? k : v;
    ushort* out = (z == 0) ? xq : (z == 1) ? xk : xv;
    int i = blockIdx.x * blockDim.x + threadIdx.x;
    if (i < n4) {
        float4 val = ((const float4*)in)[i];
        ushort4 o;
        o.x = f2bf(val.x); o.y = f2bf(val.y); o.z = f2bf(val.z); o.w = f2bf(val.w);
        ((ushort4*)out)[i] = o;
    }
}

// ---------------- W transpose + convert: Wt[n][k] = bf16(W[k][n]) ----------------
__global__ void wtrans(const float* __restrict__ W0, const float* __restrict__ W1,
                       const float* __restrict__ W2, const float* __restrict__ W3,
                       ushort* __restrict__ T0, ushort* __restrict__ T1,
                       ushort* __restrict__ T2, ushort* __restrict__ T3) {
    __shared__ float sh[32][33];
    const float* src; ushort* dst;
    switch (blockIdx.z) {
        case 0:  src = W0; dst = T0; break;
        case 1:  src = W1; dst = T1; break;
        case 2:  src = W2; dst = T2; break;
        default: src = W3; dst = T3; break;
    }
    int k0 = blockIdx.y * 32, n0 = blockIdx.x * 32;
    int tx = threadIdx.x, ty = threadIdx.y;
    sh[ty][tx] = src[(size_t)(k0 + ty) * DD + n0 + tx];
    __syncthreads();
    dst[(size_t)(n0 + ty) * DD + k0 + tx] = f2bf(sh[tx][ty]);
}

// ---------------- V transpose: Vt[bh][d][t] = Vh[bh][t][d] ----------------
__global__ __launch_bounds__(256)
void vtrans(const ushort* __restrict__ Vh, ushort* __restrict__ Vt) {
    __shared__ ushort sh[64][72];
    const int tid = threadIdx.x;
    const int bh = blockIdx.y;
    const int t0 = blockIdx.x * 64;
    const size_t base = (size_t)bh * (TT * HD);
    #pragma unroll
    for (int it = 0; it < 2; ++it) {
        int u = tid + it * 256;
        int r = u >> 3, c8 = (u & 7) * 8;
        *(uint4*)&sh[r][c8] = *(const uint4*)(Vh + base + (size_t)(t0 + r) * HD + c8);
    }
    __syncthreads();
    #pragma unroll
    for (int it = 0; it < 2; ++it) {
        int u = tid + it * 256;
        int d = u >> 3, c8 = (u & 7) * 8;
        alignas(16) ushort tmp[8];
        #pragma unroll
        for (int p = 0; p < 8; ++p) tmp[p] = sh[c8 + p][d];
        *(uint4*)(Vt + base + (size_t)d * TT + t0 + c8) = *(const uint4*)tmp;
    }
}

// ---------------- BMx128 bf16 MFMA GEMM: C = A @ Bt^T + bias ----------------
// BM=128/OUT_MODE=0: z-batched QKV, bf16 out [B,H,T,hd]. BM=64/OUT_MODE=1: fp32 out.
template<int BM, int OUT_MODE>
__global__ __launch_bounds__(256)
void gemm_mfma(const ushort* __restrict__ A0, const ushort* __restrict__ B0,
               const float* __restrict__ c0, void* __restrict__ d0,
               const ushort* __restrict__ A1, const ushort* __restrict__ B1,
               const float* __restrict__ c1, void* __restrict__ d1,
               const ushort* __restrict__ A2, const ushort* __restrict__ B2,
               const float* __restrict__ c2, void* __restrict__ d2) {
    constexpr int TI = 4;
    constexpr int TJ = (BM == 128) ? 4 : 2;
    constexpr int WC = (BM == 128) ? 2 : 4;
    __shared__ __attribute__((aligned(16))) ushort As[BM][40];
    __shared__ __attribute__((aligned(16))) ushort Bs[128][40];
    const ushort* A; const ushort* Bt; const float* bias; void* outp;
    switch (blockIdx.z) {
        case 0:  A = A0; Bt = B0; bias = c0; outp = d0; break;
        case 1:  A = A1; Bt = B1; bias = c1; outp = d1; break;
        default: A = A2; Bt = B2; bias = c2; outp = d2; break;
    }
    const int tid  = threadIdx.x;
    const int lane = tid & 63, w = tid >> 6;
    const int wr = w / WC, wc = w % WC;
    const int ln = lane & 15, quad = lane >> 4;
    const int m0 = blockIdx.y * BM, n0 = blockIdx.x * 128;

    const f32x4 zero = {0.f, 0.f, 0.f, 0.f};
    f32x4 acc[TI][TJ];
    #pragma unroll
    for (int i = 0; i < TI; ++i)
        #pragma unroll
        for (int j = 0; j < TJ; ++j) acc[i][j] = zero;

    const int sr  = tid >> 2;
    const int sc8 = (tid & 3) * 8;

    for (int kb = 0; kb < 1024; kb += 32) {
        #pragma unroll
        for (int it = 0; it < BM / 64; ++it) {
            int r = sr + it * 64;
            *(uint4*)&As[r][sc8] = *(const uint4*)(A + (size_t)(m0 + r) * 1024 + kb + sc8);
        }
        #pragma unroll
        for (int it = 0; it < 2; ++it) {
            int r = sr + it * 64;
            *(uint4*)&Bs[r][sc8] = *(const uint4*)(Bt + (size_t)(n0 + r) * 1024 + kb + sc8);
        }
        __syncthreads();
        bf16x8 af[TI], bfr[TJ];
        #pragma unroll
        for (int i = 0; i < TI; ++i)
            af[i] = as_bf8(*(const uint4*)&As[wr * 64 + i * 16 + ln][quad * 8]);
        #pragma unroll
        for (int j = 0; j < TJ; ++j)
            bfr[j] = as_bf8(*(const uint4*)&Bs[wc * (TJ * 16) + j * 16 + ln][quad * 8]);
        #pragma unroll
        for (int i = 0; i < TI; ++i)
            #pragma unroll
            for (int j = 0; j < TJ; ++j)
                acc[i][j] = __builtin_amdgcn_mfma_f32_16x16x32_bf16(af[i], bfr[j], acc[i][j], 0, 0, 0);
        __syncthreads();
    }

    #pragma unroll
    for (int j = 0; j < TJ; ++j) {
        int n = n0 + wc * (TJ * 16) + j * 16 + ln;
        float bv = bias[n];
        #pragma unroll
        for (int i = 0; i < TI; ++i) {
            #pragma unroll
            for (int r = 0; r < 4; ++r) {
                int m = m0 + wr * 64 + i * 16 + quad * 4 + r;
                float v = acc[i][j][r] + bv;
                if (OUT_MODE == 0) {
                    int b = m >> 11, t = m & 2047, h = n >> 6, d = n & 63;
                    ((ushort*)outp)[(((size_t)(b * HH + h)) * TT + t) * HD + d] = f2bf(v);
                } else {
                    ((float*)outp)[(size_t)m * 1024 + n] = v;
                }
            }
        }
    }
}

// ---------------- flash attention: barrier-free, banded ALiBi, no-max softmax ----
// Qh,Kh: [bh][t][d]   Vtg: [bh][d][t]   out: [B][T][D] bf16
__global__ __launch_bounds__(256)
void attn_kernel(const ushort* __restrict__ Qh, const ushort* __restrict__ Kh,
                 const ushort* __restrict__ Vtg, ushort* __restrict__ outp) {
    __shared__ __attribute__((aligned(16))) ushort Ps[4][32][72];
    const int tid  = threadIdx.x;
    const int lane = tid & 63, w = tid >> 6;
    const int ln = lane & 15, quad = lane >> 4;
    // heavy-first decode: h=15 blocks launch first
    const int bid = blockIdx.x;
    const int h = 15 - (bid >> 5);
    const int rr = bid & 31;
    const int b = rr & 1;
    const int qt = rr >> 1;
    const int bh = b * 16 + h;
    const int qbase0 = qt * 128;
    const int qbase = qbase0 + w * 32;
    const float slope2 = exp2f(-0.5f * (float)(h + 1)) * 1.44269504f;  // slope*log2e
    const float c1 = 0.125f * 1.44269504f;                             // scale*log2e
    const size_t base = (size_t)bh * (TT * HD);

    // ALiBi band: tiles with slope2*dist >= 26 contribute < 2^-24 -> skip
    const int D = (int)ceilf(26.0f / slope2);
    int lo = qbase0 - D;
    int kt_lo = (lo > 0) ? (lo >> 6) : 0;
    int kt_hi = (qbase0 + 128 + D + 63) >> 6;
    if (kt_hi > TT / 64) kt_hi = TT / 64;

    // Q fragments (A-layout)
    bf16x8 qa[2][2];
    #pragma unroll
    for (int g = 0; g < 2; ++g) {
        const uint4* qp = (const uint4*)(Qh + base + (size_t)(qbase + g * 16 + ln) * HD);
        qa[g][0] = as_bf8(qp[quad]);
        qa[g][1] = as_bf8(qp[4 + quad]);
    }
    const f32x4 zero = {0.f, 0.f, 0.f, 0.f};
    f32x4 o[2][4], lsum[2];
    #pragma unroll
    for (int g = 0; g < 2; ++g) {
        lsum[g] = zero;
        #pragma unroll
        for (int dn = 0; dn < 4; ++dn) o[g][dn] = zero;
    }
    bf16x8 ones;
    {
        union { ushort us[8]; bf16x8 v; } uu;
        #pragma unroll
        for (int p = 0; p < 8; ++p) uu.us[p] = 0x3F80;
        ones = uu.v;
    }
    float qrf[2][4];
    #pragma unroll
    for (int g = 0; g < 2; ++g)
        #pragma unroll
        for (int r = 0; r < 4; ++r)
            qrf[g][r] = (float)(qbase + g * 16 + quad * 4 + r);

    // per-lane fragment base pointers (16B-contiguous per lane)
    const ushort* kp = Kh  + base + (size_t)ln * HD + quad * 8;  // + kt*4096 + n*1024 + half*32
    const ushort* vp = Vtg + base + (size_t)ln * TT + quad * 8;  // + dn*32768 + kt*64 + half*32

    // K fragments double-buffered in registers
    uint4 kf[8];
    {
        const int ko = kt_lo * 4096;
        #pragma unroll
        for (int n = 0; n < 4; ++n)
            #pragma unroll
            for (int hf = 0; hf < 2; ++hf)
                kf[n * 2 + hf] = *(const uint4*)(kp + ko + n * 1024 + hf * 32);
    }

    for (int kt = kt_lo; kt < kt_hi; ++kt) {
        // V fragments for this tile (consumed late -> latency covered by QK+exp)
        uint4 vf[8];
        {
            const int vo = kt * 64;
            #pragma unroll
            for (int dn = 0; dn < 4; ++dn)
                #pragma unroll
                for (int hf = 0; hf < 2; ++hf)
                    vf[dn * 2 + hf] = *(const uint4*)(vp + dn * 32768 + vo + hf * 32);
        }
        // prefetch next K tile
        uint4 kn[8];
        {
            const int ktn = (kt + 1 < kt_hi) ? (kt + 1) : kt;
            const int ko = ktn * 4096;
            #pragma unroll
            for (int n = 0; n < 4; ++n)
                #pragma unroll
                for (int hf = 0; hf < 2; ++hf)
                    kn[n * 2 + hf] = *(const uint4*)(kp + ko + n * 1024 + hf * 32);
        }

        // S = Q K^T
        f32x4 s[2][4];
        #pragma unroll
        for (int n = 0; n < 4; ++n) {
            bf16x8 b0 = as_bf8(kf[n * 2]);
            bf16x8 b1 = as_bf8(kf[n * 2 + 1]);
            #pragma unroll
            for (int g = 0; g < 2; ++g) {
                f32x4 z = zero;
                z = __builtin_amdgcn_mfma_f32_16x16x32_bf16(qa[g][0], b0, z, 0, 0, 0);
                s[g][n] = __builtin_amdgcn_mfma_f32_16x16x32_bf16(qa[g][1], b1, z, 0, 0, 0);
            }
        }

        // p = exp2(S*c1 - slope2*|q-k|), truncate to bf16, swizzled LDS store
        #pragma unroll
        for (int n = 0; n < 4; ++n) {
            float kg = (float)(kt * 64 + n * 16 + ln);
            int bswz = ((2 * n + (ln >> 3)) ^ quad) * 8 + (ln & 7);
            #pragma unroll
            for (int g = 0; g < 2; ++g) {
                #pragma unroll
                for (int r = 0; r < 4; ++r) {
                    float d = qrf[g][r] - kg;
                    float arg = fmaf(s[g][n][r], c1, -slope2 * fabsf(d));
                    float p = EXP2(arg);
                    Ps[w][g * 16 + quad * 4 + r][bswz] = (ushort)(fasu(p) >> 16);
                }
            }
        }
        // no barrier: Ps is wave-private; compiler inserts lgkmcnt waits

        // O += P V ; lsum += P * ones
        #pragma unroll
        for (int hf = 0; hf < 2; ++hf) {
            bf16x8 ap0 = as_bf8(*(const uint4*)&Ps[w][ln]     [((hf * 4 + quad) ^ (ln >> 2)) * 8]);
            bf16x8 ap1 = as_bf8(*(const uint4*)&Ps[w][16 + ln][((hf * 4 + quad) ^ (ln >> 2)) * 8]);
            #pragma unroll
            for (int dn = 0; dn < 4; ++dn) {
                bf16x8 bv = as_bf8(vf[dn * 2 + hf]);
                o[0][dn] = __builtin_amdgcn_mfma_f32_16x16x32_bf16(ap0, bv, o[0][dn], 0, 0, 0);
                o[1][dn] = __builtin_amdgcn_mfma_f32_16x16x32_bf16(ap1, bv, o[1][dn], 0, 0, 0);
            }
            lsum[0] = __builtin_amdgcn_mfma_f32_16x16x32_bf16(ap0, ones, lsum[0], 0, 0, 0);
            lsum[1] = __builtin_amdgcn_mfma_f32_16x16x32_bf16(ap1, ones, lsum[1], 0, 0, 0);
        }

        #pragma unroll
        for (int i = 0; i < 8; ++i) kf[i] = kn[i];
    }

    // epilogue: normalize, write [B][T][D] bf16
    #pragma unroll
    for (int g = 0; g < 2; ++g) {
        #pragma unroll
        for (int r = 0; r < 4; ++r) {
            float inv = __builtin_amdgcn_rcpf(lsum[g][r]);
            int q = qbase + g * 16 + quad * 4 + r;
            size_t ob = ((size_t)(b * TT + q)) * DD + h * HD;
            #pragma unroll
            for (int dn = 0; dn < 4; ++dn)
                outp[ob + dn * 16 + ln] = f2bf(o[g][dn][r] * inv);
        }
    }
}

extern "C" void kernel_launch(void* const* d_in, const int* in_sizes, int n_in,
                              void* d_out, int out_size, void* d_ws, size_t ws_size,
                              hipStream_t stream) {
    const float* query = (const float*)d_in[0];
    const float* key   = (const float*)d_in[1];
    const float* value = (const float*)d_in[2];
    const float* Wq = (const float*)d_in[3];
    const float* bq = (const float*)d_in[4];
    const float* Wk = (const float*)d_in[5];
    const float* bk = (const float*)d_in[6];
    const float* Wv = (const float*)d_in[7];
    const float* bv = (const float*)d_in[8];
    const float* Wo = (const float*)d_in[9];
    const float* bo = (const float*)d_in[10];
    float* out = (float*)d_out;

    char* ws = (char*)d_ws;
    const size_t MB = 1024 * 1024;
    ushort* Xq  = (ushort*)(ws + 0);
    ushort* Xk  = (ushort*)(ws + 8 * MB);
    ushort* Xv  = (ushort*)(ws + 16 * MB);
    ushort* Wtq = (ushort*)(ws + 24 * MB);
    ushort* Wtk = (ushort*)(ws + 26 * MB);
    ushort* Wtv = (ushort*)(ws + 28 * MB);
    ushort* Wto = (ushort*)(ws + 30 * MB);
    ushort* Qh  = (ushort*)(ws + 32 * MB);
    ushort* Kh  = (ushort*)(ws + 40 * MB);
    ushort* Vh  = (ushort*)(ws + 48 * MB);
    ushort* Vt   = (ushort*)(ws + 8 * MB);  // reuse Xk (free after QKV gemm)
    ushort* attn = (ushort*)(ws + 0);       // reuse Xq (free after QKV gemm)

    const int n4 = (BSZ * TT * DD) / 4;
    cvt3<<<dim3(n4 / 256, 3), 256, 0, stream>>>(query, key, value, Xq, Xk, Xv, n4);
    wtrans<<<dim3(32, 32, 4), dim3(32, 32), 0, stream>>>(Wq, Wk, Wv, Wo, Wtq, Wtk, Wtv, Wto);

    // QKV projections: one z-batched launch, 768 blocks (3 blocks/CU)
    gemm_mfma<128, 0><<<dim3(8, 32, 3), 256, 0, stream>>>(
        Xq, Wtq, bq, Qh,  Xk, Wtk, bk, Kh,  Xv, Wtv, bv, Vh);

    vtrans<<<dim3(TT / 64, BSZ * HH), 256, 0, stream>>>(Vh, Vt);

    attn_kernel<<<dim3((TT / 128) * BSZ * HH), 256, 0, stream>>>(Qh, Kh, Vt, attn);

    // output projection: 64x128 tiles, 512 blocks (2 blocks/CU)
    gemm_mfma<64, 1><<<dim3(8, 64, 1), 256, 0, stream>>>(
        attn, Wto, bo, out,  attn, Wto, bo, out,  attn, Wto, bo, out);
}

// Round 4
// 275.317 us; speedup vs baseline: 1.2972x; 1.1068x over previous
//
#include <hip/hip_runtime.h>
#include <stdint.h>

#define BSZ 2
#define TT 2048
#define DD 1024
#define HH 16
#define HD 64

typedef __bf16 bf16x8 __attribute__((ext_vector_type(8)));
typedef float f32x4 __attribute__((ext_vector_type(4)));

#if __has_builtin(__builtin_amdgcn_exp2f)
#define EXP2(x) __builtin_amdgcn_exp2f(x)
#else
#define EXP2(x) exp2f(x)
#endif

__device__ __forceinline__ unsigned short f2bf(float f) {
    union { float f; unsigned u; } c; c.f = f;
    unsigned u = c.u;
    unsigned r = u + 0x7fffu + ((u >> 16) & 1u);
    return (unsigned short)(r >> 16);
}
__device__ __forceinline__ unsigned fasu(float f) {
    union { float f; unsigned u; } c; c.f = f; return c.u;
}

union U4BF { uint4 u; bf16x8 b; };
__device__ __forceinline__ bf16x8 as_bf8(uint4 v) { U4BF c; c.u = v; return c.b; }

// ---------------- fp32 -> bf16 convert, 3 tensors in one launch ----------------
__global__ void cvt3(const float* __restrict__ q, const float* __restrict__ k,
                     const float* __restrict__ v, ushort* __restrict__ xq,
                     ushort* __restrict__ xk, ushort* __restrict__ xv, int n4) {
    int z = blockIdx.y;
    const float* in = (z == 0) ? q : (z == 1) ? k : v;
    ushort* out = (z == 0) ? xq : (z == 1) ? xk : xv;
    int i = blockIdx.x * blockDim.x + threadIdx.x;
    if (i < n4) {
        float4 val = ((const float4*)in)[i];
        ushort4 o;
        o.x = f2bf(val.x); o.y = f2bf(val.y); o.z = f2bf(val.z); o.w = f2bf(val.w);
        ((ushort4*)out)[i] = o;
    }
}

// ---------------- W transpose + convert: Wt[n][k] = bf16(W[k][n]) ----------------
__global__ void wtrans(const float* __restrict__ W0, const float* __restrict__ W1,
                       const float* __restrict__ W2, const float* __restrict__ W3,
                       ushort* __restrict__ T0, ushort* __restrict__ T1,
                       ushort* __restrict__ T2, ushort* __restrict__ T3) {
    __shared__ float sh[32][33];
    const float* src; ushort* dst;
    switch (blockIdx.z) {
        case 0:  src = W0; dst = T0; break;
        case 1:  src = W1; dst = T1; break;
        case 2:  src = W2; dst = T2; break;
        default: src = W3; dst = T3; break;
    }
    int k0 = blockIdx.y * 32, n0 = blockIdx.x * 32;
    int tx = threadIdx.x, ty = threadIdx.y;
    sh[ty][tx] = src[(size_t)(k0 + ty) * DD + n0 + tx];
    __syncthreads();
    dst[(size_t)(n0 + ty) * DD + k0 + tx] = f2bf(sh[tx][ty]);
}

// ---------------- V transpose: Vt[bh][d][t] = Vh[bh][t][d] ----------------
__global__ __launch_bounds__(256)
void vtrans(const ushort* __restrict__ Vh, ushort* __restrict__ Vt) {
    __shared__ ushort sh[64][72];
    const int tid = threadIdx.x;
    const int bh = blockIdx.y;
    const int t0 = blockIdx.x * 64;
    const size_t base = (size_t)bh * (TT * HD);
    #pragma unroll
    for (int it = 0; it < 2; ++it) {
        int u = tid + it * 256;
        int r = u >> 3, c8 = (u & 7) * 8;
        *(uint4*)&sh[r][c8] = *(const uint4*)(Vh + base + (size_t)(t0 + r) * HD + c8);
    }
    __syncthreads();
    #pragma unroll
    for (int it = 0; it < 2; ++it) {
        int u = tid + it * 256;
        int d = u >> 3, c8 = (u & 7) * 8;
        alignas(16) ushort tmp[8];
        #pragma unroll
        for (int p = 0; p < 8; ++p) tmp[p] = sh[c8 + p][d];
        *(uint4*)(Vt + base + (size_t)d * TT + t0 + c8) = *(const uint4*)tmp;
    }
}

// ---------------- BMx128 bf16 MFMA GEMM: C = A @ Bt^T + bias ----------------
template<int BM, int OUT_MODE>
__global__ __launch_bounds__(256)
void gemm_mfma(const ushort* __restrict__ A0, const ushort* __restrict__ B0,
               const float* __restrict__ c0, void* __restrict__ d0,
               const ushort* __restrict__ A1, const ushort* __restrict__ B1,
               const float* __restrict__ c1, void* __restrict__ d1,
               const ushort* __restrict__ A2, const ushort* __restrict__ B2,
               const float* __restrict__ c2, void* __restrict__ d2) {
    constexpr int TI = 4;
    constexpr int TJ = (BM == 128) ? 4 : 2;
    constexpr int WC = (BM == 128) ? 2 : 4;
    __shared__ __attribute__((aligned(16))) ushort As[BM][40];
    __shared__ __attribute__((aligned(16))) ushort Bs[128][40];
    const ushort* A; const ushort* Bt; const float* bias; void* outp;
    switch (blockIdx.z) {
        case 0:  A = A0; Bt = B0; bias = c0; outp = d0; break;
        case 1:  A = A1; Bt = B1; bias = c1; outp = d1; break;
        default: A = A2; Bt = B2; bias = c2; outp = d2; break;
    }
    const int tid  = threadIdx.x;
    const int lane = tid & 63, w = tid >> 6;
    const int wr = w / WC, wc = w % WC;
    const int ln = lane & 15, quad = lane >> 4;
    const int m0 = blockIdx.y * BM, n0 = blockIdx.x * 128;

    const f32x4 zero = {0.f, 0.f, 0.f, 0.f};
    f32x4 acc[TI][TJ];
    #pragma unroll
    for (int i = 0; i < TI; ++i)
        #pragma unroll
        for (int j = 0; j < TJ; ++j) acc[i][j] = zero;

    const int sr  = tid >> 2;
    const int sc8 = (tid & 3) * 8;

    for (int kb = 0; kb < 1024; kb += 32) {
        #pragma unroll
        for (int it = 0; it < BM / 64; ++it) {
            int r = sr + it * 64;
            *(uint4*)&As[r][sc8] = *(const uint4*)(A + (size_t)(m0 + r) * 1024 + kb + sc8);
        }
        #pragma unroll
        for (int it = 0; it < 2; ++it) {
            int r = sr + it * 64;
            *(uint4*)&Bs[r][sc8] = *(const uint4*)(Bt + (size_t)(n0 + r) * 1024 + kb + sc8);
        }
        __syncthreads();
        bf16x8 af[TI], bfr[TJ];
        #pragma unroll
        for (int i = 0; i < TI; ++i)
            af[i] = as_bf8(*(const uint4*)&As[wr * 64 + i * 16 + ln][quad * 8]);
        #pragma unroll
        for (int j = 0; j < TJ; ++j)
            bfr[j] = as_bf8(*(const uint4*)&Bs[wc * (TJ * 16) + j * 16 + ln][quad * 8]);
        #pragma unroll
        for (int i = 0; i < TI; ++i)
            #pragma unroll
            for (int j = 0; j < TJ; ++j)
                acc[i][j] = __builtin_amdgcn_mfma_f32_16x16x32_bf16(af[i], bfr[j], acc[i][j], 0, 0, 0);
        __syncthreads();
    }

    #pragma unroll
    for (int j = 0; j < TJ; ++j) {
        int n = n0 + wc * (TJ * 16) + j * 16 + ln;
        float bv = bias[n];
        #pragma unroll
        for (int i = 0; i < TI; ++i) {
            #pragma unroll
            for (int r = 0; r < 4; ++r) {
                int m = m0 + wr * 64 + i * 16 + quad * 4 + r;
                float v = acc[i][j][r] + bv;
                if (OUT_MODE == 0) {
                    int b = m >> 11, t = m & 2047, h = n >> 6, d = n & 63;
                    ((ushort*)outp)[(((size_t)(b * HH + h)) * TT + t) * HD + d] = f2bf(v);
                } else {
                    ((float*)outp)[(size_t)m * 1024 + n] = v;
                }
            }
        }
    }
}

// ---------------- flash attention: k-split waves, banded ALiBi, no-max softmax ----
// Work unit = (b, h, 32 q-rows). Block = 4 waves; wave w handles 1/4 of the
// unit's k-band (partial O,l are pure sums -> mergeable). End: LDS tree-merge.
// Qh,Kh: [bh][t][d]   Vtg: [bh][d][t]   out: [B][T][D] bf16
__global__ __launch_bounds__(256)
void attn_kernel(const ushort* __restrict__ Qh, const ushort* __restrict__ Kh,
                 const ushort* __restrict__ Vtg, ushort* __restrict__ outp) {
    // Ps: ushort[4][32][72] = 18432 B ; Rbuf: float[2][64][41] = 20992 B (overlaid)
    __shared__ __attribute__((aligned(16))) char smem[20992];
    ushort (*Ps)[32][72] = (ushort (*)[32][72])smem;
    float  (*Rbuf)[64][41] = (float (*)[64][41])smem;

    const int tid  = threadIdx.x;
    const int lane = tid & 63, w = tid >> 6;     // w = k-chunk index 0..3
    const int ln = lane & 15, quad = lane >> 4;
    // heavy-first decode: h=15 blocks launch first. 128 blocks per h (2 b x 64 qt)
    const int bid = blockIdx.x;
    const int h = 15 - (bid >> 7);
    const int rr = bid & 127;
    const int b = rr & 1;
    const int qt = rr >> 1;
    const int bh = b * 16 + h;
    const int qbase = qt * 32;
    const float slope2 = exp2f(-0.5f * (float)(h + 1)) * 1.44269504f;  // slope*log2e
    const float c1 = 0.125f * 1.44269504f;                             // scale*log2e
    const size_t base = (size_t)bh * (TT * HD);

    // ALiBi band: tiles with slope2*dist >= 26 contribute < 2^-24 -> skip
    const int D = (int)ceilf(26.0f / slope2);
    int lo = qbase - D;
    int kt_lo = (lo > 0) ? (lo >> 6) : 0;
    int kt_hi = (qbase + 32 + D + 63) >> 6;
    if (kt_hi > TT / 64) kt_hi = TT / 64;
    // this wave's chunk
    const int nt = kt_hi - kt_lo;
    const int cs = (nt + 3) >> 2;
    const int my_lo = kt_lo + w * cs;
    const int my_hi = (my_lo + cs < kt_hi) ? (my_lo + cs) : kt_hi;

    // Q fragments (A-layout)
    bf16x8 qa[2][2];
    #pragma unroll
    for (int g = 0; g < 2; ++g) {
        const uint4* qp = (const uint4*)(Qh + base + (size_t)(qbase + g * 16 + ln) * HD);
        qa[g][0] = as_bf8(qp[quad]);
        qa[g][1] = as_bf8(qp[4 + quad]);
    }
    const f32x4 zero = {0.f, 0.f, 0.f, 0.f};
    f32x4 o[2][4], lsum[2];
    #pragma unroll
    for (int g = 0; g < 2; ++g) {
        lsum[g] = zero;
        #pragma unroll
        for (int dn = 0; dn < 4; ++dn) o[g][dn] = zero;
    }
    bf16x8 ones;
    {
        union { ushort us[8]; bf16x8 v; } uu;
        #pragma unroll
        for (int p = 0; p < 8; ++p) uu.us[p] = 0x3F80;
        ones = uu.v;
    }
    float qrf[2][4];
    #pragma unroll
    for (int g = 0; g < 2; ++g)
        #pragma unroll
        for (int r = 0; r < 4; ++r)
            qrf[g][r] = (float)(qbase + g * 16 + quad * 4 + r);

    const ushort* kp = Kh  + base + (size_t)ln * HD + quad * 8;
    const ushort* vp = Vtg + base + (size_t)ln * TT + quad * 8;

    if (my_lo < my_hi) {
        uint4 kf[8];
        {
            const int ko = my_lo * 4096;
            #pragma unroll
            for (int n = 0; n < 4; ++n)
                #pragma unroll
                for (int hf = 0; hf < 2; ++hf)
                    kf[n * 2 + hf] = *(const uint4*)(kp + ko + n * 1024 + hf * 32);
        }

        for (int kt = my_lo; kt < my_hi; ++kt) {
            uint4 vf[8];
            {
                const int vo = kt * 64;
                #pragma unroll
                for (int dn = 0; dn < 4; ++dn)
                    #pragma unroll
                    for (int hf = 0; hf < 2; ++hf)
                        vf[dn * 2 + hf] = *(const uint4*)(vp + dn * 32768 + vo + hf * 32);
            }
            uint4 kn[8];
            if (kt + 1 < my_hi) {
                const int ko = (kt + 1) * 4096;
                #pragma unroll
                for (int n = 0; n < 4; ++n)
                    #pragma unroll
                    for (int hf = 0; hf < 2; ++hf)
                        kn[n * 2 + hf] = *(const uint4*)(kp + ko + n * 1024 + hf * 32);
            }

            // S = Q K^T
            f32x4 s[2][4];
            #pragma unroll
            for (int n = 0; n < 4; ++n) {
                bf16x8 b0 = as_bf8(kf[n * 2]);
                bf16x8 b1 = as_bf8(kf[n * 2 + 1]);
                #pragma unroll
                for (int g = 0; g < 2; ++g) {
                    f32x4 z = zero;
                    z = __builtin_amdgcn_mfma_f32_16x16x32_bf16(qa[g][0], b0, z, 0, 0, 0);
                    s[g][n] = __builtin_amdgcn_mfma_f32_16x16x32_bf16(qa[g][1], b1, z, 0, 0, 0);
                }
            }

            // p = exp2(S*c1 - slope2*|q-k|), truncate to bf16, swizzled LDS store
            #pragma unroll
            for (int n = 0; n < 4; ++n) {
                float kg = (float)(kt * 64 + n * 16 + ln);
                int bswz = ((2 * n + (ln >> 3)) ^ quad) * 8 + (ln & 7);
                #pragma unroll
                for (int g = 0; g < 2; ++g) {
                    #pragma unroll
                    for (int r = 0; r < 4; ++r) {
                        float d = qrf[g][r] - kg;
                        float arg = fmaf(s[g][n][r], c1, -slope2 * fabsf(d));
                        float p = EXP2(arg);
                        Ps[w][g * 16 + quad * 4 + r][bswz] = (ushort)(fasu(p) >> 16);
                    }
                }
            }
            // no barrier: Ps[w] is wave-private

            // O += P V ; lsum += P * ones
            #pragma unroll
            for (int hf = 0; hf < 2; ++hf) {
                bf16x8 ap0 = as_bf8(*(const uint4*)&Ps[w][ln]     [((hf * 4 + quad) ^ (ln >> 2)) * 8]);
                bf16x8 ap1 = as_bf8(*(const uint4*)&Ps[w][16 + ln][((hf * 4 + quad) ^ (ln >> 2)) * 8]);
                #pragma unroll
                for (int dn = 0; dn < 4; ++dn) {
                    bf16x8 bv = as_bf8(vf[dn * 2 + hf]);
                    o[0][dn] = __builtin_amdgcn_mfma_f32_16x16x32_bf16(ap0, bv, o[0][dn], 0, 0, 0);
                    o[1][dn] = __builtin_amdgcn_mfma_f32_16x16x32_bf16(ap1, bv, o[1][dn], 0, 0, 0);
                }
                lsum[0] = __builtin_amdgcn_mfma_f32_16x16x32_bf16(ap0, ones, lsum[0], 0, 0, 0);
                lsum[1] = __builtin_amdgcn_mfma_f32_16x16x32_bf16(ap1, ones, lsum[1], 0, 0, 0);
            }

            #pragma unroll
            for (int i = 0; i < 8; ++i) kf[i] = kn[i];
        }
    }

    // -------- cross-wave merge of partial (o, lsum): pairwise tree --------
    __syncthreads();  // all loops done; Ps dead; Rbuf safe to write
    if (w >= 2) {
        float* dst = &Rbuf[w - 2][lane][0];
        #pragma unroll
        for (int g = 0; g < 2; ++g) {
            #pragma unroll
            for (int dn = 0; dn < 4; ++dn)
                #pragma unroll
                for (int r = 0; r < 4; ++r)
                    dst[g * 16 + dn * 4 + r] = o[g][dn][r];
            #pragma unroll
            for (int r = 0; r < 4; ++r)
                dst[32 + g * 4 + r] = lsum[g][r];
        }
    }
    __syncthreads();
    if (w < 2) {
        const float* src = &Rbuf[w][lane][0];
        #pragma unroll
        for (int g = 0; g < 2; ++g) {
            #pragma unroll
            for (int dn = 0; dn < 4; ++dn)
                #pragma unroll
                for (int r = 0; r < 4; ++r)
                    o[g][dn][r] += src[g * 16 + dn * 4 + r];
            #pragma unroll
            for (int r = 0; r < 4; ++r)
                lsum[g][r] += src[32 + g * 4 + r];
        }
    }
    __syncthreads();
    if (w == 1) {
        float* dst = &Rbuf[0][lane][0];
        #pragma unroll
        for (int g = 0; g < 2; ++g) {
            #pragma unroll
            for (int dn = 0; dn < 4; ++dn)
                #pragma unroll
                for (int r = 0; r < 4; ++r)
                    dst[g * 16 + dn * 4 + r] = o[g][dn][r];
            #pragma unroll
            for (int r = 0; r < 4; ++r)
                dst[32 + g * 4 + r] = lsum[g][r];
        }
    }
    __syncthreads();
    if (w == 0) {
        const float* src = &Rbuf[0][lane][0];
        #pragma unroll
        for (int g = 0; g < 2; ++g) {
            #pragma unroll
            for (int dn = 0; dn < 4; ++dn)
                #pragma unroll
                for (int r = 0; r < 4; ++r)
                    o[g][dn][r] += src[g * 16 + dn * 4 + r];
            #pragma unroll
            for (int r = 0; r < 4; ++r)
                lsum[g][r] += src[32 + g * 4 + r];
        }
        // normalize, write [B][T][D] bf16
        #pragma unroll
        for (int g = 0; g < 2; ++g) {
            #pragma unroll
            for (int r = 0; r < 4; ++r) {
                float inv = __builtin_amdgcn_rcpf(lsum[g][r]);
                int q = qbase + g * 16 + quad * 4 + r;
                size_t ob = ((size_t)(b * TT + q)) * DD + h * HD;
                #pragma unroll
                for (int dn = 0; dn < 4; ++dn)
                    outp[ob + dn * 16 + ln] = f2bf(o[g][dn][r] * inv);
            }
        }
    }
}

extern "C" void kernel_launch(void* const* d_in, const int* in_sizes, int n_in,
                              void* d_out, int out_size, void* d_ws, size_t ws_size,
                              hipStream_t stream) {
    const float* query = (const float*)d_in[0];
    const float* key   = (const float*)d_in[1];
    const float* value = (const float*)d_in[2];
    const float* Wq = (const float*)d_in[3];
    const float* bq = (const float*)d_in[4];
    const float* Wk = (const float*)d_in[5];
    const float* bk = (const float*)d_in[6];
    const float* Wv = (const float*)d_in[7];
    const float* bv = (const float*)d_in[8];
    const float* Wo = (const float*)d_in[9];
    const float* bo = (const float*)d_in[10];
    float* out = (float*)d_out;

    char* ws = (char*)d_ws;
    const size_t MB = 1024 * 1024;
    ushort* Xq  = (ushort*)(ws + 0);
    ushort* Xk  = (ushort*)(ws + 8 * MB);
    ushort* Xv  = (ushort*)(ws + 16 * MB);
    ushort* Wtq = (ushort*)(ws + 24 * MB);
    ushort* Wtk = (ushort*)(ws + 26 * MB);
    ushort* Wtv = (ushort*)(ws + 28 * MB);
    ushort* Wto = (ushort*)(ws + 30 * MB);
    ushort* Qh  = (ushort*)(ws + 32 * MB);
    ushort* Kh  = (ushort*)(ws + 40 * MB);
    ushort* Vh  = (ushort*)(ws + 48 * MB);
    ushort* Vt   = (ushort*)(ws + 8 * MB);  // reuse Xk (free after QKV gemm)
    ushort* attn = (ushort*)(ws + 0);       // reuse Xq (free after QKV gemm)

    const int n4 = (BSZ * TT * DD) / 4;
    cvt3<<<dim3(n4 / 256, 3), 256, 0, stream>>>(query, key, value, Xq, Xk, Xv, n4);
    wtrans<<<dim3(32, 32, 4), dim3(32, 32), 0, stream>>>(Wq, Wk, Wv, Wo, Wtq, Wtk, Wtv, Wto);

    // QKV projections: one z-batched launch, 768 blocks
    gemm_mfma<128, 0><<<dim3(8, 32, 3), 256, 0, stream>>>(
        Xq, Wtq, bq, Qh,  Xk, Wtk, bk, Kh,  Xv, Wtv, bv, Vh);

    vtrans<<<dim3(TT / 64, BSZ * HH), 256, 0, stream>>>(Vh, Vt);

    // 2048 blocks: (b,h,32q) x 4 k-chunk waves
    attn_kernel<<<dim3((TT / 32) * BSZ * HH), 256, 0, stream>>>(Qh, Kh, Vt, attn);

    // output projection: 64x128 tiles, 512 blocks
    gemm_mfma<64, 1><<<dim3(8, 64, 1), 256, 0, stream>>>(
        attn, Wto, bo, out,  attn, Wto, bo, out,  attn, Wto, bo, out);
}

// Round 5
// 248.495 us; speedup vs baseline: 1.4372x; 1.1079x over previous
//
#include <hip/hip_runtime.h>
#include <stdint.h>

#define BSZ 2
#define TT 2048
#define DD 1024
#define HH 16
#define HD 64

typedef __bf16 bf16x8 __attribute__((ext_vector_type(8)));
typedef float f32x4 __attribute__((ext_vector_type(4)));

#if __has_builtin(__builtin_amdgcn_exp2f)
#define EXP2(x) __builtin_amdgcn_exp2f(x)
#else
#define EXP2(x) exp2f(x)
#endif

__device__ __forceinline__ unsigned short f2bf(float f) {
    union { float f; unsigned u; } c; c.f = f;
    unsigned u = c.u;
    unsigned r = u + 0x7fffu + ((u >> 16) & 1u);
    return (unsigned short)(r >> 16);
}
__device__ __forceinline__ unsigned fasu(float f) {
    union { float f; unsigned u; } c; c.f = f; return c.u;
}

union U4BF { uint4 u; bf16x8 b; };
__device__ __forceinline__ bf16x8 as_bf8(uint4 v) { U4BF c; c.u = v; return c.b; }

// ---- async global->LDS, 16B per lane; LDS dst = wave-uniform base + lane*16 ----
#if __has_builtin(__builtin_amdgcn_global_load_lds)
__device__ __forceinline__ void gl_lds16(const ushort* g, ushort* l) {
    __builtin_amdgcn_global_load_lds(
        (const __attribute__((address_space(1))) uint32_t*)g,
        (__attribute__((address_space(3))) uint32_t*)l, 16, 0, 0);
}
#define GLL_LANE 1
#else
__device__ __forceinline__ void gl_lds16_fallback(const ushort* g, ushort* l, int lane) {
    *(uint4*)(l + lane * 8) = *(const uint4*)(g);
}
#define GLL_LANE 0
#endif

// ---------------- fp32 -> bf16 convert, 3 tensors in one launch ----------------
__global__ void cvt3(const float* __restrict__ q, const float* __restrict__ k,
                     const float* __restrict__ v, ushort* __restrict__ xq,
                     ushort* __restrict__ xk, ushort* __restrict__ xv, int n4) {
    int z = blockIdx.y;
    const float* in = (z == 0) ? q : (z == 1) ? k : v;
    ushort* out = (z == 0) ? xq : (z == 1) ? xk : xv;
    int i = blockIdx.x * blockDim.x + threadIdx.x;
    if (i < n4) {
        float4 val = ((const float4*)in)[i];
        ushort4 o;
        o.x = f2bf(val.x); o.y = f2bf(val.y); o.z = f2bf(val.z); o.w = f2bf(val.w);
        ((ushort4*)out)[i] = o;
    }
}

// ---------------- W transpose + convert: Wt[n][k] = bf16(W[k][n]) ----------------
__global__ void wtrans(const float* __restrict__ W0, const float* __restrict__ W1,
                       const float* __restrict__ W2, const float* __restrict__ W3,
                       ushort* __restrict__ T0, ushort* __restrict__ T1,
                       ushort* __restrict__ T2, ushort* __restrict__ T3) {
    __shared__ float sh[32][33];
    const float* src; ushort* dst;
    switch (blockIdx.z) {
        case 0:  src = W0; dst = T0; break;
        case 1:  src = W1; dst = T1; break;
        case 2:  src = W2; dst = T2; break;
        default: src = W3; dst = T3; break;
    }
    int k0 = blockIdx.y * 32, n0 = blockIdx.x * 32;
    int tx = threadIdx.x, ty = threadIdx.y;
    sh[ty][tx] = src[(size_t)(k0 + ty) * DD + n0 + tx];
    __syncthreads();
    dst[(size_t)(n0 + ty) * DD + k0 + tx] = f2bf(sh[tx][ty]);
}

// ---------------- BMx128 bf16 MFMA GEMM with global_load_lds staging ----------------
// OUT_MODE 0: z-batched QKV. z<2 -> bf16 [bh][t][d]; z==2 -> bf16 Vt [bh][d][t].
// OUT_MODE 1: fp32 out row-major [4096][1024].
template<int BM, int OUT_MODE>
__global__ __launch_bounds__(256)
void gemm_mfma(const ushort* __restrict__ A0, const ushort* __restrict__ B0,
               const float* __restrict__ c0, void* __restrict__ d0,
               const ushort* __restrict__ A1, const ushort* __restrict__ B1,
               const float* __restrict__ c1, void* __restrict__ d1,
               const ushort* __restrict__ A2, const ushort* __restrict__ B2,
               const float* __restrict__ c2, void* __restrict__ d2) {
    constexpr int TI = 4;
    constexpr int TJ = (BM == 128) ? 4 : 2;
    constexpr int WC = (BM == 128) ? 2 : 4;
    __shared__ __attribute__((aligned(16))) ushort As[BM][32];
    __shared__ __attribute__((aligned(16))) ushort Bs[128][32];
    const ushort* A; const ushort* Bt; const float* bias; void* outp;
    const int z = blockIdx.z;
    switch (z) {
        case 0:  A = A0; Bt = B0; bias = c0; outp = d0; break;
        case 1:  A = A1; Bt = B1; bias = c1; outp = d1; break;
        default: A = A2; Bt = B2; bias = c2; outp = d2; break;
    }
    const int tid  = threadIdx.x;
    const int lane = tid & 63, w = tid >> 6;
    const int wr = w / WC, wc = w % WC;
    const int ln = lane & 15, quad = lane >> 4;
    const int m0 = blockIdx.y * BM, n0 = blockIdx.x * 128;

    const f32x4 zero = {0.f, 0.f, 0.f, 0.f};
    f32x4 acc[TI][TJ];
    #pragma unroll
    for (int i = 0; i < TI; ++i)
        #pragma unroll
        for (int j = 0; j < TJ; ++j) acc[i][j] = zero;

    const int lr  = lane >> 2;        // 0..15 row within 16-row stripe
    const int lc8 = (lane & 3) * 8;   // 0,8,16,24

    for (int kb = 0; kb < 1024; kb += 32) {
        #pragma unroll
        for (int it = 0; it < BM / 64; ++it) {
            int r0 = it * 64 + w * 16;
#if GLL_LANE
            gl_lds16(A + (size_t)(m0 + r0 + lr) * 1024 + kb + lc8, &As[r0][0]);
#else
            gl_lds16_fallback(A + (size_t)(m0 + r0 + lr) * 1024 + kb + lc8, &As[r0][0], lane);
#endif
        }
        #pragma unroll
        for (int it = 0; it < 2; ++it) {
            int r0 = it * 64 + w * 16;
#if GLL_LANE
            gl_lds16(Bt + (size_t)(n0 + r0 + lr) * 1024 + kb + lc8, &Bs[r0][0]);
#else
            gl_lds16_fallback(Bt + (size_t)(n0 + r0 + lr) * 1024 + kb + lc8, &Bs[r0][0], lane);
#endif
        }
        __syncthreads();
        bf16x8 af[TI], bfr[TJ];
        #pragma unroll
        for (int i = 0; i < TI; ++i)
            af[i] = as_bf8(*(const uint4*)&As[wr * 64 + i * 16 + ln][quad * 8]);
        #pragma unroll
        for (int j = 0; j < TJ; ++j)
            bfr[j] = as_bf8(*(const uint4*)&Bs[wc * (TJ * 16) + j * 16 + ln][quad * 8]);
        #pragma unroll
        for (int i = 0; i < TI; ++i)
            #pragma unroll
            for (int j = 0; j < TJ; ++j)
                acc[i][j] = __builtin_amdgcn_mfma_f32_16x16x32_bf16(af[i], bfr[j], acc[i][j], 0, 0, 0);
        __syncthreads();
    }

    #pragma unroll
    for (int j = 0; j < TJ; ++j) {
        int n = n0 + wc * (TJ * 16) + j * 16 + ln;
        float bv = bias[n];
        #pragma unroll
        for (int i = 0; i < TI; ++i) {
            int mb = m0 + wr * 64 + i * 16 + quad * 4;
            if (OUT_MODE == 0 && z == 2) {
                // V: write transposed Vt[bh][d][t], t = mb..mb+3 contiguous
                int b = mb >> 11, t = mb & 2047, h = n >> 6, d = n & 63;
                ushort4 pk;
                pk.x = f2bf(acc[i][j][0] + bv);
                pk.y = f2bf(acc[i][j][1] + bv);
                pk.z = f2bf(acc[i][j][2] + bv);
                pk.w = f2bf(acc[i][j][3] + bv);
                *(ushort4*)((ushort*)outp + ((size_t)((b * HH + h) * HD + d)) * TT + t) = pk;
            } else {
                #pragma unroll
                for (int r = 0; r < 4; ++r) {
                    int m = mb + r;
                    float v = acc[i][j][r] + bv;
                    if (OUT_MODE == 0) {
                        int b = m >> 11, t = m & 2047, h = n >> 6, d = n & 63;
                        ((ushort*)outp)[(((size_t)(b * HH + h)) * TT + t) * HD + d] = f2bf(v);
                    } else {
                        ((float*)outp)[(size_t)m * 1024 + n] = v;
                    }
                }
            }
        }
    }
}

// ---------------- flash attention: persistent folded schedule ----------------
// 1024 blocks, all co-resident; block p runs items p and 2047-p (heavy-first
// sorted), pair sums ~balanced. Item = (b,h,32 q-rows); 4 waves k-split; LDS merge.
// Qh,Kh: [bh][t][d]   Vtg: [bh][d][t]   out: [B][T][D] bf16
__global__ __launch_bounds__(256)
void attn_kernel(const ushort* __restrict__ Qh, const ushort* __restrict__ Kh,
                 const ushort* __restrict__ Vtg, ushort* __restrict__ outp) {
    // Ps: ushort[4][32][72] = 18432 B ; Rbuf: float[2][64][41] = 20992 B (overlaid)
    __shared__ __attribute__((aligned(16))) char smem[20992];
    ushort (*Ps)[32][72] = (ushort (*)[32][72])smem;
    float  (*Rbuf)[64][41] = (float (*)[64][41])smem;

    const int tid  = threadIdx.x;
    const int lane = tid & 63, w = tid >> 6;     // w = k-chunk index 0..3
    const int ln = lane & 15, quad = lane >> 4;

    bf16x8 ones;
    {
        union { ushort us[8]; bf16x8 v; } uu;
        #pragma unroll
        for (int p = 0; p < 8; ++p) uu.us[p] = 0x3F80;
        ones = uu.v;
    }
    const f32x4 zero = {0.f, 0.f, 0.f, 0.f};
    const float c1 = 0.125f * 1.44269504f;  // scale*log2e

    for (int sel = 0; sel < 2; ++sel) {
        __syncthreads();  // protect LDS reuse across items
        const int item = sel ? (2047 - (int)blockIdx.x) : (int)blockIdx.x;
        const int h = 15 - (item >> 7);
        const int rr = item & 127;
        const int b = rr & 1;
        const int qt = rr >> 1;
        const int bh = b * 16 + h;
        const int qbase = qt * 32;
        const float slope2 = exp2f(-0.5f * (float)(h + 1)) * 1.44269504f;
        const size_t base = (size_t)bh * (TT * HD);

        // ALiBi band: tiles with slope2*dist >= 22 contribute < ~2^-17 of mass
        const int D = (int)ceilf(22.0f / slope2);
        int lo = qbase - D;
        int kt_lo = (lo > 0) ? (lo >> 6) : 0;
        int kt_hi = (qbase + 32 + D + 63) >> 6;
        if (kt_hi > TT / 64) kt_hi = TT / 64;
        const int nt = kt_hi - kt_lo;
        const int cs = (nt + 3) >> 2;
        const int my_lo = kt_lo + w * cs;
        const int my_hi = (my_lo + cs < kt_hi) ? (my_lo + cs) : kt_hi;

        // Q fragments (A-layout)
        bf16x8 qa[2][2];
        #pragma unroll
        for (int g = 0; g < 2; ++g) {
            const uint4* qp = (const uint4*)(Qh + base + (size_t)(qbase + g * 16 + ln) * HD);
            qa[g][0] = as_bf8(qp[quad]);
            qa[g][1] = as_bf8(qp[4 + quad]);
        }
        f32x4 o[2][4], lsum[2];
        #pragma unroll
        for (int g = 0; g < 2; ++g) {
            lsum[g] = zero;
            #pragma unroll
            for (int dn = 0; dn < 4; ++dn) o[g][dn] = zero;
        }
        float qrf[2][4];
        #pragma unroll
        for (int g = 0; g < 2; ++g)
            #pragma unroll
            for (int r = 0; r < 4; ++r)
                qrf[g][r] = (float)(qbase + g * 16 + quad * 4 + r);

        const ushort* kp = Kh  + base + (size_t)ln * HD + quad * 8;
        const ushort* vp = Vtg + base + (size_t)ln * TT + quad * 8;

        if (my_lo < my_hi) {
            uint4 kf[8];
            {
                const int ko = my_lo * 4096;
                #pragma unroll
                for (int n = 0; n < 4; ++n)
                    #pragma unroll
                    for (int hf = 0; hf < 2; ++hf)
                        kf[n * 2 + hf] = *(const uint4*)(kp + ko + n * 1024 + hf * 32);
            }

            for (int kt = my_lo; kt < my_hi; ++kt) {
                uint4 vf[8];
                {
                    const int vo = kt * 64;
                    #pragma unroll
                    for (int dn = 0; dn < 4; ++dn)
                        #pragma unroll
                        for (int hf = 0; hf < 2; ++hf)
                            vf[dn * 2 + hf] = *(const uint4*)(vp + dn * 32768 + vo + hf * 32);
                }
                uint4 kn[8];
                if (kt + 1 < my_hi) {
                    const int ko = (kt + 1) * 4096;
                    #pragma unroll
                    for (int n = 0; n < 4; ++n)
                        #pragma unroll
                        for (int hf = 0; hf < 2; ++hf)
                            kn[n * 2 + hf] = *(const uint4*)(kp + ko + n * 1024 + hf * 32);
                }

                // S = Q K^T
                f32x4 s[2][4];
                #pragma unroll
                for (int n = 0; n < 4; ++n) {
                    bf16x8 b0 = as_bf8(kf[n * 2]);
                    bf16x8 b1 = as_bf8(kf[n * 2 + 1]);
                    #pragma unroll
                    for (int g = 0; g < 2; ++g) {
                        f32x4 zz = zero;
                        zz = __builtin_amdgcn_mfma_f32_16x16x32_bf16(qa[g][0], b0, zz, 0, 0, 0);
                        s[g][n] = __builtin_amdgcn_mfma_f32_16x16x32_bf16(qa[g][1], b1, zz, 0, 0, 0);
                    }
                }

                // p = exp2(S*c1 - slope2*|q-k|), truncate bf16, swizzled LDS store
                #pragma unroll
                for (int n = 0; n < 4; ++n) {
                    float kg = (float)(kt * 64 + n * 16 + ln);
                    int bswz = ((2 * n + (ln >> 3)) ^ quad) * 8 + (ln & 7);
                    #pragma unroll
                    for (int g = 0; g < 2; ++g) {
                        #pragma unroll
                        for (int r = 0; r < 4; ++r) {
                            float d = qrf[g][r] - kg;
                            float arg = fmaf(s[g][n][r], c1, -slope2 * fabsf(d));
                            float p = EXP2(arg);
                            Ps[w][g * 16 + quad * 4 + r][bswz] = (ushort)(fasu(p) >> 16);
                        }
                    }
                }
                // no barrier: Ps[w] is wave-private

                // O += P V ; lsum += P * ones
                #pragma unroll
                for (int hf = 0; hf < 2; ++hf) {
                    bf16x8 ap0 = as_bf8(*(const uint4*)&Ps[w][ln]     [((hf * 4 + quad) ^ (ln >> 2)) * 8]);
                    bf16x8 ap1 = as_bf8(*(const uint4*)&Ps[w][16 + ln][((hf * 4 + quad) ^ (ln >> 2)) * 8]);
                    #pragma unroll
                    for (int dn = 0; dn < 4; ++dn) {
                        bf16x8 bv = as_bf8(vf[dn * 2 + hf]);
                        o[0][dn] = __builtin_amdgcn_mfma_f32_16x16x32_bf16(ap0, bv, o[0][dn], 0, 0, 0);
                        o[1][dn] = __builtin_amdgcn_mfma_f32_16x16x32_bf16(ap1, bv, o[1][dn], 0, 0, 0);
                    }
                    lsum[0] = __builtin_amdgcn_mfma_f32_16x16x32_bf16(ap0, ones, lsum[0], 0, 0, 0);
                    lsum[1] = __builtin_amdgcn_mfma_f32_16x16x32_bf16(ap1, ones, lsum[1], 0, 0, 0);
                }

                #pragma unroll
                for (int i = 0; i < 8; ++i) kf[i] = kn[i];
            }
        }

        // -------- cross-wave merge of partial (o, lsum): pairwise tree --------
        __syncthreads();
        if (w >= 2) {
            float* dst = &Rbuf[w - 2][lane][0];
            #pragma unroll
            for (int g = 0; g < 2; ++g) {
                #pragma unroll
                for (int dn = 0; dn < 4; ++dn)
                    #pragma unroll
                    for (int r = 0; r < 4; ++r)
                        dst[g * 16 + dn * 4 + r] = o[g][dn][r];
                #pragma unroll
                for (int r = 0; r < 4; ++r)
                    dst[32 + g * 4 + r] = lsum[g][r];
            }
        }
        __syncthreads();
        if (w < 2) {
            const float* src = &Rbuf[w][lane][0];
            #pragma unroll
            for (int g = 0; g < 2; ++g) {
                #pragma unroll
                for (int dn = 0; dn < 4; ++dn)
                    #pragma unroll
                    for (int r = 0; r < 4; ++r)
                        o[g][dn][r] += src[g * 16 + dn * 4 + r];
                #pragma unroll
                for (int r = 0; r < 4; ++r)
                    lsum[g][r] += src[32 + g * 4 + r];
            }
        }
        __syncthreads();
        if (w == 1) {
            float* dst = &Rbuf[0][lane][0];
            #pragma unroll
            for (int g = 0; g < 2; ++g) {
                #pragma unroll
                for (int dn = 0; dn < 4; ++dn)
                    #pragma unroll
                    for (int r = 0; r < 4; ++r)
                        dst[g * 16 + dn * 4 + r] = o[g][dn][r];
                #pragma unroll
                for (int r = 0; r < 4; ++r)
                    dst[32 + g * 4 + r] = lsum[g][r];
            }
        }
        __syncthreads();
        if (w == 0) {
            const float* src = &Rbuf[0][lane][0];
            #pragma unroll
            for (int g = 0; g < 2; ++g) {
                #pragma unroll
                for (int dn = 0; dn < 4; ++dn)
                    #pragma unroll
                    for (int r = 0; r < 4; ++r)
                        o[g][dn][r] += src[g * 16 + dn * 4 + r];
                #pragma unroll
                for (int r = 0; r < 4; ++r)
                    lsum[g][r] += src[32 + g * 4 + r];
            }
            // normalize, write [B][T][D] bf16
            #pragma unroll
            for (int g = 0; g < 2; ++g) {
                #pragma unroll
                for (int r = 0; r < 4; ++r) {
                    float inv = __builtin_amdgcn_rcpf(lsum[g][r]);
                    int q = qbase + g * 16 + quad * 4 + r;
                    size_t ob = ((size_t)(b * TT + q)) * DD + h * HD;
                    #pragma unroll
                    for (int dn = 0; dn < 4; ++dn)
                        outp[ob + dn * 16 + ln] = f2bf(o[g][dn][r] * inv);
                }
            }
        }
    }
}

extern "C" void kernel_launch(void* const* d_in, const int* in_sizes, int n_in,
                              void* d_out, int out_size, void* d_ws, size_t ws_size,
                              hipStream_t stream) {
    const float* query = (const float*)d_in[0];
    const float* key   = (const float*)d_in[1];
    const float* value = (const float*)d_in[2];
    const float* Wq = (const float*)d_in[3];
    const float* bq = (const float*)d_in[4];
    const float* Wk = (const float*)d_in[5];
    const float* bk = (const float*)d_in[6];
    const float* Wv = (const float*)d_in[7];
    const float* bv = (const float*)d_in[8];
    const float* Wo = (const float*)d_in[9];
    const float* bo = (const float*)d_in[10];
    float* out = (float*)d_out;

    char* ws = (char*)d_ws;
    const size_t MB = 1024 * 1024;
    ushort* Xq  = (ushort*)(ws + 0);
    ushort* Xk  = (ushort*)(ws + 8 * MB);
    ushort* Xv  = (ushort*)(ws + 16 * MB);
    ushort* Wtq = (ushort*)(ws + 24 * MB);
    ushort* Wtk = (ushort*)(ws + 26 * MB);
    ushort* Wtv = (ushort*)(ws + 28 * MB);
    ushort* Wto = (ushort*)(ws + 30 * MB);
    ushort* Qh  = (ushort*)(ws + 32 * MB);
    ushort* Kh  = (ushort*)(ws + 40 * MB);
    ushort* Vt  = (ushort*)(ws + 48 * MB);  // written transposed by gemm z==2
    ushort* attn = (ushort*)(ws + 0);       // reuse Xq (free after QKV gemm)

    const int n4 = (BSZ * TT * DD) / 4;
    cvt3<<<dim3(n4 / 256, 3), 256, 0, stream>>>(query, key, value, Xq, Xk, Xv, n4);
    wtrans<<<dim3(32, 32, 4), dim3(32, 32), 0, stream>>>(Wq, Wk, Wv, Wo, Wtq, Wtk, Wtv, Wto);

    // QKV projections: one z-batched launch; z==2 writes V transposed
    gemm_mfma<128, 0><<<dim3(8, 32, 3), 256, 0, stream>>>(
        Xq, Wtq, bq, Qh,  Xk, Wtk, bk, Kh,  Xv, Wtv, bv, Vt);

    // persistent: 1024 blocks, 2 folded items each
    attn_kernel<<<dim3(1024), 256, 0, stream>>>(Qh, Kh, Vt, attn);

    // output projection: 64x128 tiles, 512 blocks
    gemm_mfma<64, 1><<<dim3(8, 64, 1), 256, 0, stream>>>(
        attn, Wto, bo, out,  attn, Wto, bo, out,  attn, Wto, bo, out);
}